// Round 1
// baseline (13891.565 us; speedup 1.0000x reference)
//
#include <hip/hip_runtime.h>
#include <cstddef>

#define EPS 1e-5f

constexpr int Bsz = 256;
constexpr int Nn  = 100;
constexpr int Cc  = 512;
constexpr int BN_ROWS = Bsz * Nn; // 25600

// ---------------- per-column stats over M rows (M <= 256), grid = Ccols ----------------
__global__ void colstats_kernel(const float* __restrict__ x, int M, int Ccols,
                                const float* __restrict__ g, const float* __restrict__ bb,
                                float* __restrict__ s, float* __restrict__ t) {
    int c = blockIdx.x;
    int r = threadIdx.x;
    float v = (r < M) ? x[(size_t)r * Ccols + c] : 0.f;
    __shared__ float ssum[256], ssq[256];
    ssum[r] = v; ssq[r] = v * v;
    __syncthreads();
    for (int off = 128; off > 0; off >>= 1) {
        if (r < off) { ssum[r] += ssum[r + off]; ssq[r] += ssq[r + off]; }
        __syncthreads();
    }
    if (r == 0) {
        float m   = ssum[0] / M;
        float var = ssq[0] / M - m * m;
        float sc  = g[c] * rsqrtf(var + EPS);
        s[c] = sc;
        t[c] = bb[c] - m * sc;
    }
}

// ---------------- per-node-channel stats: mean over (B, D) for each n, grid = Nn ----------------
__global__ void chstats_kernel(const float* __restrict__ x, int D,
                               const float* __restrict__ g, const float* __restrict__ bb,
                               float* __restrict__ s, float* __restrict__ t) {
    int n = blockIdx.x;
    int tid = threadIdx.x;
    int total = Bsz * D;
    float sum = 0.f, sq = 0.f;
    for (int idx = tid; idx < total; idx += blockDim.x) {
        int b = idx / D, d = idx - b * D;
        float v = x[((size_t)b * Nn + n) * D + d];
        sum += v; sq += v * v;
    }
    __shared__ float ssum[256], ssq[256];
    ssum[tid] = sum; ssq[tid] = sq;
    __syncthreads();
    for (int off = 128; off > 0; off >>= 1) {
        if (tid < off) { ssum[tid] += ssum[tid + off]; ssq[tid] += ssq[tid + off]; }
        __syncthreads();
    }
    if (tid == 0) {
        float m   = ssum[0] / total;
        float var = ssq[0] / total - m * m;
        float sc  = g[n] * rsqrtf(var + EPS);
        s[n] = sc;
        t[n] = bb[n] - m * sc;
    }
}

// ---------------- generic 64x64 tiled GEMM ----------------
// C[m,n] = act( sum_k normA(A[m,k]) * B(k,n) + bias[n] )
// TB=true : B is (N x K) row-major -> B[n*ldb + k]   (C = A * B^T)
// TB=false: B is (K x N) row-major -> B[k*ldb + n]   (C = A * B)
// NORM: 0 none, 1 per-col (s[k],t[k]), 2 per-row (s[m % mod])
template <int NORM, bool ELU, bool TB>
__global__ void gemm_kernel(const float* __restrict__ A, const float* __restrict__ B,
                            const float* __restrict__ bias,
                            const float* __restrict__ s, const float* __restrict__ t,
                            int M, int N, int K, int lda, int ldb, int mod,
                            float* __restrict__ Cout, int ldc, int c_off,
                            long strideA, long strideB, long strideC) {
    const float* Ab = A + (size_t)blockIdx.z * strideA;
    const float* Bb = B + (size_t)blockIdx.z * strideB;
    float*       Cb = Cout + (size_t)blockIdx.z * strideC;

    __shared__ float As[16][65];
    __shared__ float Bs[16][65];

    int bm = blockIdx.x * 64, bn = blockIdx.y * 64;
    int tid = threadIdx.x;
    int tm = (tid >> 4) << 2;  // 0..60
    int tn = (tid & 15) << 2;  // 0..60
    float acc[4][4] = {};

    for (int k0 = 0; k0 < K; k0 += 16) {
#pragma unroll
        for (int i = 0; i < 4; i++) {
            int idx = tid + i * 256;
            // A tile: As[kk][row]
            {
                int rr = idx >> 4, kk = idx & 15;
                int gr = bm + rr, gk = k0 + kk;
                float av = 0.f;
                if (gr < M && gk < K) {
                    av = Ab[(size_t)gr * lda + gk];
                    if constexpr (NORM == 1) av = av * s[gk] + t[gk];
                    else if constexpr (NORM == 2) { int n_ = gr % mod; av = av * s[n_] + t[n_]; }
                }
                As[kk][rr] = av;
            }
            // B tile: Bs[kk][col]
            if constexpr (TB) {
                int nn = idx >> 4, kk = idx & 15;
                int gn = bn + nn, gk = k0 + kk;
                Bs[kk][nn] = (gn < N && gk < K) ? Bb[(size_t)gn * ldb + gk] : 0.f;
            } else {
                int kk = idx >> 6, nn = idx & 63;
                int gn = bn + nn, gk = k0 + kk;
                Bs[kk][nn] = (gn < N && gk < K) ? Bb[(size_t)gk * ldb + gn] : 0.f;
            }
        }
        __syncthreads();
#pragma unroll
        for (int kk = 0; kk < 16; kk++) {
            float a0[4], b0[4];
#pragma unroll
            for (int i = 0; i < 4; i++) a0[i] = As[kk][tm + i];
#pragma unroll
            for (int j = 0; j < 4; j++) b0[j] = Bs[kk][tn + j];
#pragma unroll
            for (int i = 0; i < 4; i++)
#pragma unroll
                for (int j = 0; j < 4; j++)
                    acc[i][j] = fmaf(a0[i], b0[j], acc[i][j]);
        }
        __syncthreads();
    }

#pragma unroll
    for (int i = 0; i < 4; i++) {
        int gr = bm + tm + i;
        if (gr >= M) continue;
#pragma unroll
        for (int j = 0; j < 4; j++) {
            int gn = bn + tn + j;
            if (gn >= N) continue;
            float v = acc[i][j] + (bias ? bias[gn] : 0.f);
            if constexpr (ELU) v = v > 0.f ? v : expm1f(v);
            Cb[(size_t)gr * ldc + c_off + gn] = v;
        }
    }
}

// ---------------- bbox head: (B*N,4) -> (B*N,32) with per-n BN + elu, writes V cols 480..511 ----------------
__global__ void bbox_kernel(const float* __restrict__ pos, const float* __restrict__ w,
                            const float* __restrict__ bias, const float* __restrict__ s,
                            const float* __restrict__ t, float* __restrict__ V) {
    __shared__ float ws[32][4];
    int tid = threadIdx.x; // 256
    if (tid < 128) ws[tid >> 2][tid & 3] = w[tid];
    __syncthreads();
    int r = blockIdx.x * 8 + (tid >> 5);
    int o = tid & 31;
    int n = r % Nn;
    float sc = s[n], sh = t[n];
    float p0 = pos[(size_t)r * 4 + 0] * sc + sh;
    float p1 = pos[(size_t)r * 4 + 1] * sc + sh;
    float p2 = pos[(size_t)r * 4 + 2] * sc + sh;
    float p3 = pos[(size_t)r * 4 + 3] * sc + sh;
    float acc = bias[o] + p0 * ws[o][0] + p1 * ws[o][1] + p2 * ws[o][2] + p3 * ws[o][3];
    acc = acc > 0.f ? acc : expm1f(acc);
    V[(size_t)r * Cc + 480 + o] = acc;
}

// ---------------- row softmax over Nn=100 entries, one wave per row ----------------
__global__ void softmax_rows_kernel(float* __restrict__ R) {
    size_t row = blockIdx.x;
    float* p = R + row * Nn;
    int tid = threadIdx.x; // 64
    float e0 = (tid < Nn) ? p[tid] : -1e30f;
    float e1 = (tid + 64 < Nn) ? p[tid + 64] : -1e30f;
    float mx = fmaxf(e0, e1);
    for (int off = 32; off > 0; off >>= 1) mx = fmaxf(mx, __shfl_xor(mx, off, 64));
    float x0 = (tid < Nn) ? expf(e0 - mx) : 0.f;
    float x1 = (tid + 64 < Nn) ? expf(e1 - mx) : 0.f;
    float sm = x0 + x1;
    for (int off = 32; off > 0; off >>= 1) sm += __shfl_xor(sm, off, 64);
    float inv = 1.f / sm;
    if (tid < Nn) p[tid] = x0 * inv;
    if (tid + 64 < Nn) p[tid + 64] = x1 * inv;
}

// ---------------- zero small buffer ----------------
__global__ void zero_kernel(float* __restrict__ p, int n) {
    int i = blockIdx.x * blockDim.x + threadIdx.x;
    if (i < n) p[i] = 0.f;
}

// ---------------- channel stats partials for Wy (25600 x 512): grid (8, 32) ----------------
__global__ void wy_partial_kernel(const float* __restrict__ Wy, float* __restrict__ part) {
    int tx = threadIdx.x & 63;
    int ty = threadIdx.x >> 6;
    int c  = blockIdx.x * 64 + tx;
    int r0 = blockIdx.y * 800;
    float sum = 0.f, sq = 0.f;
    for (int r = r0 + ty; r < r0 + 800; r += 4) {
        float v = Wy[(size_t)r * Cc + c];
        sum += v; sq += v * v;
    }
    __shared__ float ss[256], s2[256];
    ss[threadIdx.x] = sum; s2[threadIdx.x] = sq;
    __syncthreads();
    if (ty == 0) {
        sum = ss[tx] + ss[tx + 64] + ss[tx + 128] + ss[tx + 192];
        sq  = s2[tx] + s2[tx + 64] + s2[tx + 128] + s2[tx + 192];
        atomicAdd(&part[c], sum);
        atomicAdd(&part[Cc + c], sq);
    }
}

__global__ void wy_finalize_kernel(const float* __restrict__ part,
                                   const float* __restrict__ g, const float* __restrict__ bb,
                                   float* __restrict__ s, float* __restrict__ t) {
    int c = blockIdx.x * blockDim.x + threadIdx.x;
    if (c >= Cc) return;
    float m   = part[c] / BN_ROWS;
    float var = part[Cc + c] / BN_ROWS - m * m;
    float sc  = g[c] * rsqrtf(var + EPS);
    s[c] = sc;
    t[c] = bb[c] - m * sc;
}

// ---------------- residual: V += Wy*s[c] + t[c] ----------------
__global__ void residual_kernel(float* __restrict__ V, const float* __restrict__ Wy,
                                const float* __restrict__ s, const float* __restrict__ t) {
    size_t total = (size_t)BN_ROWS * Cc;
    for (size_t i = (size_t)blockIdx.x * blockDim.x + threadIdx.x; i < total;
         i += (size_t)gridDim.x * blockDim.x) {
        int c = (int)(i & (Cc - 1));
        V[i] += Wy[i] * s[c] + t[c];
    }
}

// ---------------- l2norm over node dim + mean -> ALL[:, 512:1024] ----------------
__global__ void l2norm_mean_kernel(const float* __restrict__ V, float* __restrict__ ALL) {
    int b = blockIdx.x;
    int c = threadIdx.x; // 512
    float sum = 0.f, sq = 0.f;
    const float* p = V + (size_t)b * Nn * Cc + c;
    for (int n = 0; n < Nn; n++) {
        float v = p[(size_t)n * Cc];
        sum += v; sq += v * v;
    }
    ALL[(size_t)b * 1536 + 512 + c] = sum / (Nn * sqrtf(sq));
}

// ---------------- final: BN(all_feats) @ ff_w.T + ff_b -> (256,2) ----------------
__global__ void final_kernel(const float* __restrict__ ALL, const float* __restrict__ s,
                             const float* __restrict__ t, const float* __restrict__ w,
                             const float* __restrict__ bias, float* __restrict__ out) {
    int b = blockIdx.x;
    int tid = threadIdx.x; // 256
    float p0 = 0.f, p1 = 0.f;
    for (int k = tid; k < 1536; k += 256) {
        float af = ALL[(size_t)b * 1536 + k] * s[k] + t[k];
        p0 += af * w[k];
        p1 += af * w[1536 + k];
    }
    __shared__ float s0[256], s1[256];
    s0[tid] = p0; s1[tid] = p1;
    __syncthreads();
    for (int off = 128; off > 0; off >>= 1) {
        if (tid < off) { s0[tid] += s0[tid + off]; s1[tid] += s1[tid + off]; }
        __syncthreads();
    }
    if (tid == 0) {
        out[b * 2 + 0] = s0[0] + bias[0];
        out[b * 2 + 1] = s1[0] + bias[1];
    }
}

extern "C" void kernel_launch(void* const* d_in, const int* in_sizes, int n_in,
                              void* d_out, int out_size, void* d_ws, size_t ws_size,
                              hipStream_t stream) {
    const float* img   = (const float*)d_in[0];
    const float* txt   = (const float*)d_in[1];
    const float* node  = (const float*)d_in[2];
    const float* pos   = (const float*)d_in[3];
    const float* swinbn_g = (const float*)d_in[4];
    const float* swinbn_b = (const float*)d_in[5];
    const float* swinfc_w = (const float*)d_in[6];
    const float* swinfc_b = (const float*)d_in[7];
    const float* bntext_g = (const float*)d_in[8];
    const float* bntext_b = (const float*)d_in[9];
    const float* fctext_w = (const float*)d_in[10];
    const float* fctext_b = (const float*)d_in[11];
    const float* bngat_g  = (const float*)d_in[12];
    const float* bngat_b  = (const float*)d_in[13];
    const float* fcgat_w  = (const float*)d_in[14];
    const float* fcgat_b  = (const float*)d_in[15];
    const float* bnbbox_g = (const float*)d_in[16];
    const float* bnbbox_b = (const float*)d_in[17];
    const float* fcbbox_w = (const float*)d_in[18];
    const float* fcbbox_b = (const float*)d_in[19];
    const float* gcn_theta_w = (const float*)d_in[20];
    const float* gcn_theta_b = (const float*)d_in[21];
    const float* gcn_phi_w   = (const float*)d_in[22];
    const float* gcn_phi_b   = (const float*)d_in[23];
    const float* gcn_g_w     = (const float*)d_in[24];
    const float* gcn_g_b     = (const float*)d_in[25];
    const float* gcn_W_w     = (const float*)d_in[26];
    const float* gcn_W_b     = (const float*)d_in[27];
    const float* gcn_bn_g    = (const float*)d_in[28];
    const float* gcn_bn_b    = (const float*)d_in[29];
    const float* ffbn_g = (const float*)d_in[30];
    const float* ffbn_b = (const float*)d_in[31];
    const float* ff_w   = (const float*)d_in[32];
    const float* ff_b   = (const float*)d_in[33];

    float* ws = (float*)d_ws;
    const size_t VN = (size_t)BN_ROWS * Cc; // 13,107,200
    float* V   = ws;
    float* T0  = V + VN;
    float* T1  = T0 + VN;
    float* Abuf = T1 + VN;                     // 2,560,000
    float* ALL  = Abuf + (size_t)Bsz * Nn * Nn; // 393,216
    float* st   = ALL + (size_t)Bsz * 1536;
    float* s_img = st;            float* t_img = s_img + 1024;
    float* s_txt = t_img + 1024;  float* t_txt = s_txt + 768;
    float* s_nd  = t_txt + 768;   float* t_nd  = s_nd + 128;
    float* s_bb  = t_nd + 128;    float* t_bb  = s_bb + 128;
    float* s_g   = t_bb + 128;    float* t_g   = s_g + 512;
    float* part  = t_g + 512;     // 1024
    float* s_ff  = part + 1024;   float* t_ff  = s_ff + 1536;

    dim3 blk(256);

    // input BN stats
    colstats_kernel<<<1024, 256, 0, stream>>>(img, 256, 1024, swinbn_g, swinbn_b, s_img, t_img);
    colstats_kernel<<<768, 256, 0, stream>>>(txt, 256, 768, bntext_g, bntext_b, s_txt, t_txt);
    chstats_kernel<<<100, 256, 0, stream>>>(node, 768, bngat_g, bngat_b, s_nd, t_nd);
    chstats_kernel<<<100, 256, 0, stream>>>(pos, 4, bnbbox_g, bnbbox_b, s_bb, t_bb);

    // heads
    gemm_kernel<1, true, true><<<dim3(4, 8, 1), blk, 0, stream>>>(
        img, swinfc_w, swinfc_b, s_img, t_img, 256, 512, 1024, 1024, 1024, 0,
        ALL, 1536, 0, 0, 0, 0);
    gemm_kernel<1, true, true><<<dim3(4, 8, 1), blk, 0, stream>>>(
        txt, fctext_w, fctext_b, s_txt, t_txt, 256, 512, 768, 768, 768, 0,
        ALL, 1536, 1024, 0, 0, 0);
    gemm_kernel<2, true, true><<<dim3(400, 8, 1), blk, 0, stream>>>(
        node, fcgat_w, fcgat_b, s_nd, t_nd, 25600, 480, 768, 768, 768, 100,
        V, 512, 0, 0, 0, 0);
    bbox_kernel<<<3200, 256, 0, stream>>>(pos, fcbbox_w, fcbbox_b, s_bb, t_bb, V);

    // 8 GCN blocks
    for (int i = 0; i < 8; i++) {
        const float* thw = gcn_theta_w + (size_t)i * Cc * Cc;
        const float* thb = gcn_theta_b + (size_t)i * Cc;
        const float* phw = gcn_phi_w + (size_t)i * Cc * Cc;
        const float* phb = gcn_phi_b + (size_t)i * Cc;
        const float* gw  = gcn_g_w + (size_t)i * Cc * Cc;
        const float* gb  = gcn_g_b + (size_t)i * Cc;
        const float* Ww  = gcn_W_w + (size_t)i * Cc * Cc;
        const float* Wb  = gcn_W_b + (size_t)i * Cc;

        // T0 = theta(V), T1 = phi(V)
        gemm_kernel<0, false, true><<<dim3(400, 8, 1), blk, 0, stream>>>(
            V, thw, thb, nullptr, nullptr, 25600, 512, 512, 512, 512, 0,
            T0, 512, 0, 0, 0, 0);
        gemm_kernel<0, false, true><<<dim3(400, 8, 1), blk, 0, stream>>>(
            V, phw, phb, nullptr, nullptr, 25600, 512, 512, 512, 512, 0,
            T1, 512, 0, 0, 0, 0);
        // A = batched T0 @ T1^T (per-b: 100x512 @ 512x100)
        gemm_kernel<0, false, true><<<dim3(2, 2, 256), blk, 0, stream>>>(
            T0, T1, nullptr, nullptr, nullptr, 100, 100, 512, 512, 512, 0,
            Abuf, 100, 0, (long)Nn * Cc, (long)Nn * Cc, (long)Nn * Nn);
        softmax_rows_kernel<<<25600, 64, 0, stream>>>(Abuf);
        // T1 = g(V)   (phi no longer needed)
        gemm_kernel<0, false, true><<<dim3(400, 8, 1), blk, 0, stream>>>(
            V, gw, gb, nullptr, nullptr, 25600, 512, 512, 512, 512, 0,
            T1, 512, 0, 0, 0, 0);
        // T0 = batched A @ T1 (per-b: 100x100 @ 100x512), overwrite theta
        gemm_kernel<0, false, false><<<dim3(2, 8, 256), blk, 0, stream>>>(
            Abuf, T1, nullptr, nullptr, nullptr, 100, 512, 100, 100, 512, 0,
            T0, 512, 0, (long)Nn * Nn, (long)Nn * Cc, (long)Nn * Cc);
        // T1 = T0 @ W^T + bW
        gemm_kernel<0, false, true><<<dim3(400, 8, 1), blk, 0, stream>>>(
            T0, Ww, Wb, nullptr, nullptr, 25600, 512, 512, 512, 512, 0,
            T1, 512, 0, 0, 0, 0);
        // channel BN stats of T1, then V += bn(T1)
        zero_kernel<<<4, 256, 0, stream>>>(part, 1024);
        wy_partial_kernel<<<dim3(8, 32, 1), 256, 0, stream>>>(T1, part);
        wy_finalize_kernel<<<2, 256, 0, stream>>>(part, gcn_bn_g + (size_t)i * Cc,
                                                  gcn_bn_b + (size_t)i * Cc, s_g, t_g);
        residual_kernel<<<2048, 256, 0, stream>>>(V, T1, s_g, t_g);
    }

    // l2norm over node dim + mean
    l2norm_mean_kernel<<<256, 512, 0, stream>>>(V, ALL);
    // final BN + tiny FC
    colstats_kernel<<<1536, 256, 0, stream>>>(ALL, 256, 1536, ffbn_g, ffbn_b, s_ff, t_ff);
    final_kernel<<<256, 256, 0, stream>>>(ALL, s_ff, t_ff, ff_w, ff_b, (float*)d_out);
}

// Round 2
// 7561.896 us; speedup vs baseline: 1.8370x; 1.8370x over previous
//
#include <hip/hip_runtime.h>
#include <cstddef>

#define EPS 1e-5f

constexpr int Bsz = 256;
constexpr int Nn  = 100;
constexpr int Cc  = 512;
constexpr int BN_ROWS = Bsz * Nn; // 25600

__device__ __forceinline__ void gload_lds16(const void* g, void* l) {
    __builtin_amdgcn_global_load_lds(
        (const __attribute__((address_space(1))) void*)g,
        (__attribute__((address_space(3))) void*)l, 16, 0, 0);
}

// ---------------- per-column stats over M rows (M <= 256), grid = Ccols ----------------
__global__ void colstats_kernel(const float* __restrict__ x, int M, int Ccols,
                                const float* __restrict__ g, const float* __restrict__ bb,
                                float* __restrict__ s, float* __restrict__ t) {
    int c = blockIdx.x;
    int r = threadIdx.x;
    float v = (r < M) ? x[(size_t)r * Ccols + c] : 0.f;
    __shared__ float ssum[256], ssq[256];
    ssum[r] = v; ssq[r] = v * v;
    __syncthreads();
    for (int off = 128; off > 0; off >>= 1) {
        if (r < off) { ssum[r] += ssum[r + off]; ssq[r] += ssq[r + off]; }
        __syncthreads();
    }
    if (r == 0) {
        float m   = ssum[0] / M;
        float var = ssq[0] / M - m * m;
        float sc  = g[c] * rsqrtf(var + EPS);
        s[c] = sc;
        t[c] = bb[c] - m * sc;
    }
}

// ---------------- per-node-channel stats: mean over (B, D) for each n, grid = Nn ----------------
__global__ void chstats_kernel(const float* __restrict__ x, int D,
                               const float* __restrict__ g, const float* __restrict__ bb,
                               float* __restrict__ s, float* __restrict__ t) {
    int n = blockIdx.x;
    int tid = threadIdx.x;
    int total = Bsz * D;
    float sum = 0.f, sq = 0.f;
    for (int idx = tid; idx < total; idx += blockDim.x) {
        int b = idx / D, d = idx - b * D;
        float v = x[((size_t)b * Nn + n) * D + d];
        sum += v; sq += v * v;
    }
    __shared__ float ssum[256], ssq[256];
    ssum[tid] = sum; ssq[tid] = sq;
    __syncthreads();
    for (int off = 128; off > 0; off >>= 1) {
        if (tid < off) { ssum[tid] += ssum[tid + off]; ssq[tid] += ssq[tid + off]; }
        __syncthreads();
    }
    if (tid == 0) {
        float m   = ssum[0] / total;
        float var = ssq[0] / total - m * m;
        float sc  = g[n] * rsqrtf(var + EPS);
        s[n] = sc;
        t[n] = bb[n] - m * sc;
    }
}

// ================= fast 128x128 tiled fp32 GEMM, 8x8 micro-tile =================
// C[m, outcol] = act( sum_k a(m,k) * b(k,n) + bias )
// TA=true : A is (K x M) row-major (k-major)  -> staged linearly via global_load_lds
// TA=false: A is (M x K) row-major            -> reg-staged with transpose (+NORM)
// TB=true : B is (N x K) row-major            -> reg-staged with transpose (N-guarded)
// TB=false: B is (K x N) row-major            -> staged linearly via global_load_lds
// Dual-B: blockIdx.y < nsplit uses B0, else B1 (same ldb). Requires M%128==0, K%16==0.
// For !TB paths, N of that operand must be a multiple of 128 relative to its tile.
template <int NORM, bool ELU, bool TA, bool TB>
__global__ __launch_bounds__(256) void gemm128_kernel(
    const float* __restrict__ A, const float* __restrict__ B0,
    const float* __restrict__ B1, int nsplit,
    const float* __restrict__ bias,
    const float* __restrict__ s, const float* __restrict__ t,
    int M, int N, int K, int lda, int ldb, int mod,
    float* __restrict__ C, int ldc, int c_off) {
    __shared__ float As[16 * 132];
    __shared__ float Bs[16 * 132];
    constexpr int AS = TA ? 128 : 132;
    constexpr int BS = TB ? 132 : 128;

    int by = blockIdx.y;
    const float* B = (by < nsplit) ? B0 : B1;
    int bn = (by < nsplit ? by : by - nsplit) * 128;
    int bm = blockIdx.x * 128;
    int outcol0 = c_off + by * 128;

    int tid = threadIdx.x;
    int lane = tid & 63, wave = tid >> 6;
    int tx = tid & 15, ty = tid >> 4;

    float acc[8][8] = {};

    for (int k0 = 0; k0 < K; k0 += 16) {
        // ---- stage A ----
        if constexpr (TA) {
#pragma unroll
            for (int i = 0; i < 2; i++) {
                int row = k0 + i * 8 + wave * 2 + (lane >> 5);
                const float* gp = A + (size_t)row * lda + bm + (lane & 31) * 4;
                gload_lds16(gp, (char*)As + ((i * 8 + wave * 2) * 128) * 4);
            }
        } else {
#pragma unroll
            for (int i = 0; i < 2; i++) {
                int id = tid + i * 256;
                int row = id >> 2, q = id & 3;
                int gr = bm + row;
                float4 f = *(const float4*)(A + (size_t)gr * lda + k0 + q * 4);
                if constexpr (NORM == 1) {
                    int kb = k0 + q * 4;
                    f.x = f.x * s[kb] + t[kb];     f.y = f.y * s[kb + 1] + t[kb + 1];
                    f.z = f.z * s[kb + 2] + t[kb + 2]; f.w = f.w * s[kb + 3] + t[kb + 3];
                } else if constexpr (NORM == 2) {
                    int n_ = gr % mod; float sc = s[n_], sh = t[n_];
                    f.x = f.x * sc + sh; f.y = f.y * sc + sh;
                    f.z = f.z * sc + sh; f.w = f.w * sc + sh;
                }
                As[(q * 4 + 0) * AS + row] = f.x;
                As[(q * 4 + 1) * AS + row] = f.y;
                As[(q * 4 + 2) * AS + row] = f.z;
                As[(q * 4 + 3) * AS + row] = f.w;
            }
        }
        // ---- stage B ----
        if constexpr (!TB) {
#pragma unroll
            for (int i = 0; i < 2; i++) {
                int row = k0 + i * 8 + wave * 2 + (lane >> 5);
                const float* gp = B + (size_t)row * ldb + bn + (lane & 31) * 4;
                gload_lds16(gp, (char*)Bs + ((i * 8 + wave * 2) * 128) * 4);
            }
        } else {
#pragma unroll
            for (int i = 0; i < 2; i++) {
                int id = tid + i * 256;
                int row = id >> 2, q = id & 3;
                int gn = bn + row;
                float4 f = make_float4(0.f, 0.f, 0.f, 0.f);
                if (gn < N) f = *(const float4*)(B + (size_t)gn * ldb + k0 + q * 4);
                Bs[(q * 4 + 0) * BS + row] = f.x;
                Bs[(q * 4 + 1) * BS + row] = f.y;
                Bs[(q * 4 + 2) * BS + row] = f.z;
                Bs[(q * 4 + 3) * BS + row] = f.w;
            }
        }
        __syncthreads();
#pragma unroll
        for (int kk = 0; kk < 16; kk++) {
            float4 a0 = *(const float4*)&As[kk * AS + ty * 4];
            float4 a1 = *(const float4*)&As[kk * AS + ty * 4 + 64];
            float4 b0 = *(const float4*)&Bs[kk * BS + tx * 4];
            float4 b1 = *(const float4*)&Bs[kk * BS + tx * 4 + 64];
            float av[8] = {a0.x, a0.y, a0.z, a0.w, a1.x, a1.y, a1.z, a1.w};
            float bv[8] = {b0.x, b0.y, b0.z, b0.w, b1.x, b1.y, b1.z, b1.w};
#pragma unroll
            for (int i = 0; i < 8; i++)
#pragma unroll
                for (int j = 0; j < 8; j++)
                    acc[i][j] = fmaf(av[i], bv[j], acc[i][j]);
        }
        __syncthreads();
    }

    // epilogue
#pragma unroll
    for (int i = 0; i < 8; i++) {
        int r = ty * 4 + (i & 3) + ((i & 4) ? 64 : 0);
        int gr = bm + r;
        float* crow = C + (size_t)gr * ldc + outcol0;
#pragma unroll
        for (int h = 0; h < 2; h++) {
            int cl = tx * 4 + h * 64;
            int gcol = bn + cl;  // column within B's N
            if constexpr (TB) { if (gcol >= N) continue; }
            float4 o;
            o.x = acc[i][h * 4 + 0]; o.y = acc[i][h * 4 + 1];
            o.z = acc[i][h * 4 + 2]; o.w = acc[i][h * 4 + 3];
            if (bias) {
                o.x += bias[gcol]; o.y += bias[gcol + 1];
                o.z += bias[gcol + 2]; o.w += bias[gcol + 3];
            }
            if constexpr (ELU) {
                o.x = o.x > 0.f ? o.x : expm1f(o.x);
                o.y = o.y > 0.f ? o.y : expm1f(o.y);
                o.z = o.z > 0.f ? o.z : expm1f(o.z);
                o.w = o.w > 0.f ? o.w : expm1f(o.w);
            }
            *(float4*)(crow + cl) = o;
        }
    }
}

// ---------------- generic 64x64 tiled GEMM (small/batched cases) ----------------
template <int NORM, bool ELU, bool TB, int CT>
__global__ void gemm_kernel(const float* __restrict__ A, const float* __restrict__ B,
                            const float* __restrict__ bias,
                            const float* __restrict__ s, const float* __restrict__ t,
                            const float* __restrict__ ct,
                            int M, int N, int K, int lda, int ldb, int mod,
                            float* __restrict__ Cout, int ldc, int c_off,
                            long strideA, long strideB, long strideC) {
    const float* Ab = A + (size_t)blockIdx.z * strideA;
    const float* Bb = B + (size_t)blockIdx.z * strideB;
    float*       Cb = Cout + (size_t)blockIdx.z * strideC;

    __shared__ float As[16][65];
    __shared__ float Bs[16][65];

    int bm = blockIdx.x * 64, bn = blockIdx.y * 64;
    int tid = threadIdx.x;
    int tm = (tid >> 4) << 2;
    int tn = (tid & 15) << 2;
    float acc[4][4] = {};

    for (int k0 = 0; k0 < K; k0 += 16) {
#pragma unroll
        for (int i = 0; i < 4; i++) {
            int idx = tid + i * 256;
            {
                int rr = idx >> 4, kk = idx & 15;
                int gr = bm + rr, gk = k0 + kk;
                float av = 0.f;
                if (gr < M && gk < K) {
                    av = Ab[(size_t)gr * lda + gk];
                    if constexpr (NORM == 1) av = av * s[gk] + t[gk];
                    else if constexpr (NORM == 2) { int n_ = gr % mod; av = av * s[n_] + t[n_]; }
                }
                As[kk][rr] = av;
            }
            if constexpr (TB) {
                int nn = idx >> 4, kk = idx & 15;
                int gn = bn + nn, gk = k0 + kk;
                Bs[kk][nn] = (gn < N && gk < K) ? Bb[(size_t)gn * ldb + gk] : 0.f;
            } else {
                int kk = idx >> 6, nn = idx & 63;
                int gn = bn + nn, gk = k0 + kk;
                Bs[kk][nn] = (gn < N && gk < K) ? Bb[(size_t)gk * ldb + gn] : 0.f;
            }
        }
        __syncthreads();
#pragma unroll
        for (int kk = 0; kk < 16; kk++) {
            float a0[4], b0[4];
#pragma unroll
            for (int i = 0; i < 4; i++) a0[i] = As[kk][tm + i];
#pragma unroll
            for (int j = 0; j < 4; j++) b0[j] = Bs[kk][tn + j];
#pragma unroll
            for (int i = 0; i < 4; i++)
#pragma unroll
                for (int j = 0; j < 4; j++)
                    acc[i][j] = fmaf(a0[i], b0[j], acc[i][j]);
        }
        __syncthreads();
    }

#pragma unroll
    for (int i = 0; i < 4; i++) {
        int gr = bm + tm + i;
        if (gr >= M) continue;
#pragma unroll
        for (int j = 0; j < 4; j++) {
            int gn = bn + tn + j;
            if (gn >= N) continue;
            float v = acc[i][j] + (bias ? bias[gn] : 0.f);
            if constexpr (CT) v += ct[(size_t)blockIdx.z * Nn + gn];
            if constexpr (ELU) v = v > 0.f ? v : expm1f(v);
            Cb[(size_t)gr * ldc + c_off + gn] = v;
        }
    }
}

// ---------------- bbox head ----------------
__global__ void bbox_kernel(const float* __restrict__ pos, const float* __restrict__ w,
                            const float* __restrict__ bias, const float* __restrict__ s,
                            const float* __restrict__ t, float* __restrict__ V) {
    __shared__ float ws[32][4];
    int tid = threadIdx.x;
    if (tid < 128) ws[tid >> 2][tid & 3] = w[tid];
    __syncthreads();
    int r = blockIdx.x * 8 + (tid >> 5);
    int o = tid & 31;
    int n = r % Nn;
    float sc = s[n], sh = t[n];
    float p0 = pos[(size_t)r * 4 + 0] * sc + sh;
    float p1 = pos[(size_t)r * 4 + 1] * sc + sh;
    float p2 = pos[(size_t)r * 4 + 2] * sc + sh;
    float p3 = pos[(size_t)r * 4 + 3] * sc + sh;
    float acc = bias[o] + p0 * ws[o][0] + p1 * ws[o][1] + p2 * ws[o][2] + p3 * ws[o][3];
    acc = acc > 0.f ? acc : expm1f(acc);
    V[(size_t)r * Cc + 480 + o] = acc;
}

// ---------------- row softmax over Nn=100 entries ----------------
__global__ void softmax_rows_kernel(float* __restrict__ R) {
    size_t row = blockIdx.x;
    float* p = R + row * Nn;
    int tid = threadIdx.x; // 64
    float e0 = (tid < Nn) ? p[tid] : -1e30f;
    float e1 = (tid + 64 < Nn) ? p[tid + 64] : -1e30f;
    float mx = fmaxf(e0, e1);
    for (int off = 32; off > 0; off >>= 1) mx = fmaxf(mx, __shfl_xor(mx, off, 64));
    float x0 = (tid < Nn) ? expf(e0 - mx) : 0.f;
    float x1 = (tid + 64 < Nn) ? expf(e1 - mx) : 0.f;
    float sm = x0 + x1;
    for (int off = 32; off > 0; off >>= 1) sm += __shfl_xor(sm, off, 64);
    float inv = 1.f / sm;
    if (tid < Nn) p[tid] = x0 * inv;
    if (tid + 64 < Nn) p[tid + 64] = x1 * inv;
}

// ---------------- small compose helpers ----------------
// q2[c] = sum_j phi[j,c] * thb[j]
__global__ void q2_kernel(const float* __restrict__ phi, const float* __restrict__ thb,
                          float* __restrict__ q2) {
    int c = blockIdx.x * 256 + threadIdx.x;
    float acc = 0.f;
    for (int j = 0; j < Cc; j++) acc += phi[(size_t)j * Cc + c] * thb[j];
    q2[c] = acc;
}
// cc[o] = sum_j W[o,j] * gb[j] + Wb[o]
__global__ void cconst_kernel(const float* __restrict__ W, const float* __restrict__ gb,
                              const float* __restrict__ Wb, float* __restrict__ cc) {
    int o = blockIdx.x;
    int l = threadIdx.x; // 64
    float acc = 0.f;
    for (int j = l; j < Cc; j += 64) acc += W[(size_t)o * Cc + j] * gb[j];
    for (int off = 32; off > 0; off >>= 1) acc += __shfl_xor(acc, off, 64);
    if (l == 0) cc[o] = acc + Wb[o];
}
// ct[r] = V[r,:] . q2
__global__ void colterm_kernel(const float* __restrict__ V, const float* __restrict__ q2,
                               float* __restrict__ ct) {
    int r = blockIdx.x * 4 + (threadIdx.x >> 6);
    int l = threadIdx.x & 63;
    const float* p = V + (size_t)r * Cc;
    float acc = 0.f;
    for (int c = l; c < Cc; c += 64) acc += p[c] * q2[c];
    for (int off = 32; off > 0; off >>= 1) acc += __shfl_xor(acc, off, 64);
    if (l == 0) ct[r] = acc;
}

// ---------------- deterministic channel-BN stats for Wy (25600 x 512 in ld-strided buf) ----------------
__global__ void wy_partial_kernel(const float* __restrict__ Wy, int ldw, float* __restrict__ part) {
    int tx = threadIdx.x & 63;
    int ty = threadIdx.x >> 6;
    int c  = blockIdx.x * 64 + tx;
    int r0 = blockIdx.y * 800;
    float sum = 0.f, sq = 0.f;
    for (int r = r0 + ty; r < r0 + 800; r += 4) {
        float v = Wy[(size_t)r * ldw + c];
        sum += v; sq += v * v;
    }
    __shared__ float ss[256], s2[256];
    ss[threadIdx.x] = sum; s2[threadIdx.x] = sq;
    __syncthreads();
    if (ty == 0) {
        sum = ss[tx] + ss[tx + 64] + ss[tx + 128] + ss[tx + 192];
        sq  = s2[tx] + s2[tx + 64] + s2[tx + 128] + s2[tx + 192];
        part[((size_t)blockIdx.y * 2 + 0) * Cc + c] = sum;
        part[((size_t)blockIdx.y * 2 + 1) * Cc + c] = sq;
    }
}

__global__ void wy_finalize_kernel(const float* __restrict__ part,
                                   const float* __restrict__ g, const float* __restrict__ bb,
                                   float* __restrict__ s, float* __restrict__ t) {
    int c = blockIdx.x * 256 + threadIdx.x;
    if (c >= Cc) return;
    float sum = 0.f, sq = 0.f;
    for (int y = 0; y < 32; y++) {
        sum += part[((size_t)y * 2 + 0) * Cc + c];
        sq  += part[((size_t)y * 2 + 1) * Cc + c];
    }
    float m   = sum / BN_ROWS;
    float var = sq / BN_ROWS - m * m;
    float sc  = g[c] * rsqrtf(var + EPS);
    s[c] = sc;
    t[c] = bb[c] - m * sc;
}

// ---------------- residual: V += Wy*s[c] + t[c] (vectorized) ----------------
__global__ void residual_kernel(float* __restrict__ V, const float* __restrict__ Wy, int ldw,
                                const float* __restrict__ s, const float* __restrict__ t) {
    size_t total4 = (size_t)BN_ROWS * Cc / 4;
    for (size_t i4 = (size_t)blockIdx.x * blockDim.x + threadIdx.x; i4 < total4;
         i4 += (size_t)gridDim.x * blockDim.x) {
        int row = (int)(i4 >> 7);
        int c = (int)(i4 & 127) * 4;
        float4 w = *(const float4*)(Wy + (size_t)row * ldw + c);
        float4 sv = *(const float4*)(s + c);
        float4 tv = *(const float4*)(t + c);
        float4 v = *(float4*)(V + (size_t)row * Cc + c);
        v.x += w.x * sv.x + tv.x; v.y += w.y * sv.y + tv.y;
        v.z += w.z * sv.z + tv.z; v.w += w.w * sv.w + tv.w;
        *(float4*)(V + (size_t)row * Cc + c) = v;
    }
}

// ---------------- l2norm over node dim + mean -> ALL[:, 512:1024] ----------------
__global__ void l2norm_mean_kernel(const float* __restrict__ V, float* __restrict__ ALL) {
    int b = blockIdx.x;
    int c = threadIdx.x; // 512
    float sum = 0.f, sq = 0.f;
    const float* p = V + (size_t)b * Nn * Cc + c;
    for (int n = 0; n < Nn; n++) {
        float v = p[(size_t)n * Cc];
        sum += v; sq += v * v;
    }
    ALL[(size_t)b * 1536 + 512 + c] = sum / (Nn * sqrtf(sq));
}

// ---------------- final: BN(all_feats) @ ff_w.T + ff_b -> (256,2) ----------------
__global__ void final_kernel(const float* __restrict__ ALL, const float* __restrict__ s,
                             const float* __restrict__ t, const float* __restrict__ w,
                             const float* __restrict__ bias, float* __restrict__ out) {
    int b = blockIdx.x;
    int tid = threadIdx.x; // 256
    float p0 = 0.f, p1 = 0.f;
    for (int k = tid; k < 1536; k += 256) {
        float af = ALL[(size_t)b * 1536 + k] * s[k] + t[k];
        p0 += af * w[k];
        p1 += af * w[1536 + k];
    }
    __shared__ float s0[256], s1[256];
    s0[tid] = p0; s1[tid] = p1;
    __syncthreads();
    for (int off = 128; off > 0; off >>= 1) {
        if (tid < off) { s0[tid] += s0[tid + off]; s1[tid] += s1[tid + off]; }
        __syncthreads();
    }
    if (tid == 0) {
        out[b * 2 + 0] = s0[0] + bias[0];
        out[b * 2 + 1] = s1[0] + bias[1];
    }
}

extern "C" void kernel_launch(void* const* d_in, const int* in_sizes, int n_in,
                              void* d_out, int out_size, void* d_ws, size_t ws_size,
                              hipStream_t stream) {
    const float* img   = (const float*)d_in[0];
    const float* txt   = (const float*)d_in[1];
    const float* node  = (const float*)d_in[2];
    const float* pos   = (const float*)d_in[3];
    const float* swinbn_g = (const float*)d_in[4];
    const float* swinbn_b = (const float*)d_in[5];
    const float* swinfc_w = (const float*)d_in[6];
    const float* swinfc_b = (const float*)d_in[7];
    const float* bntext_g = (const float*)d_in[8];
    const float* bntext_b = (const float*)d_in[9];
    const float* fctext_w = (const float*)d_in[10];
    const float* fctext_b = (const float*)d_in[11];
    const float* bngat_g  = (const float*)d_in[12];
    const float* bngat_b  = (const float*)d_in[13];
    const float* fcgat_w  = (const float*)d_in[14];
    const float* fcgat_b  = (const float*)d_in[15];
    const float* bnbbox_g = (const float*)d_in[16];
    const float* bnbbox_b = (const float*)d_in[17];
    const float* fcbbox_w = (const float*)d_in[18];
    const float* fcbbox_b = (const float*)d_in[19];
    const float* gcn_theta_w = (const float*)d_in[20];
    const float* gcn_theta_b = (const float*)d_in[21];
    const float* gcn_phi_w   = (const float*)d_in[22];
    const float* gcn_phi_b   = (const float*)d_in[23];
    const float* gcn_g_w     = (const float*)d_in[24];
    const float* gcn_g_b     = (const float*)d_in[25];
    const float* gcn_W_w     = (const float*)d_in[26];
    const float* gcn_W_b     = (const float*)d_in[27];
    const float* gcn_bn_g    = (const float*)d_in[28];
    const float* gcn_bn_b    = (const float*)d_in[29];
    const float* ffbn_g = (const float*)d_in[30];
    const float* ffbn_b = (const float*)d_in[31];
    const float* ff_w   = (const float*)d_in[32];
    const float* ff_b   = (const float*)d_in[33];

    float* ws = (float*)d_ws;
    const size_t VN = (size_t)BN_ROWS * Cc;       // 13,107,200
    float* V    = ws;
    float* TZ   = V + VN;                         // 26,214,400 (25600 x 1024)
    float* Abuf = TZ + VN * 2;                    // 2,560,000
    float* Mw   = Abuf;                           // reuse: dead once R is written
    float* WGT  = Abuf + (size_t)Cc * Cc;         // reuse
    float* ALL  = Abuf + (size_t)Bsz * Nn * Nn;   // 393,216
    float* ct   = ALL + (size_t)Bsz * 1536;       // 25,600
    float* part = ct + BN_ROWS;                   // 32,768
    float* st   = part + 64 * Cc;
    float* s_img = st;            float* t_img = s_img + 1024;
    float* s_txt = t_img + 1024;  float* t_txt = s_txt + 768;
    float* s_nd  = t_txt + 768;   float* t_nd  = s_nd + 128;
    float* s_bb  = t_nd + 128;    float* t_bb  = s_bb + 128;
    float* s_g   = t_bb + 128;    float* t_g   = s_g + 512;
    float* s_ff  = t_g + 512;     float* t_ff  = s_ff + 1536;
    float* q2    = t_ff + 1536;   float* cc    = q2 + 512;

    dim3 blk(256);

    // input BN stats
    colstats_kernel<<<1024, 256, 0, stream>>>(img, 256, 1024, swinbn_g, swinbn_b, s_img, t_img);
    colstats_kernel<<<768, 256, 0, stream>>>(txt, 256, 768, bntext_g, bntext_b, s_txt, t_txt);
    chstats_kernel<<<100, 256, 0, stream>>>(node, 768, bngat_g, bngat_b, s_nd, t_nd);
    chstats_kernel<<<100, 256, 0, stream>>>(pos, 4, bnbbox_g, bnbbox_b, s_bb, t_bb);

    // heads
    gemm_kernel<1, true, true, 0><<<dim3(4, 8, 1), blk, 0, stream>>>(
        img, swinfc_w, swinfc_b, s_img, t_img, nullptr, 256, 512, 1024, 1024, 1024, 0,
        ALL, 1536, 0, 0, 0, 0);
    gemm_kernel<1, true, true, 0><<<dim3(4, 8, 1), blk, 0, stream>>>(
        txt, fctext_w, fctext_b, s_txt, t_txt, nullptr, 256, 512, 768, 768, 768, 0,
        ALL, 1536, 1024, 0, 0, 0);
    // fcgat: (25600 x 768) -> V[:, 0:480], per-node BN + elu
    gemm128_kernel<2, true, false, true><<<dim3(200, 4, 1), blk, 0, stream>>>(
        node, fcgat_w, nullptr, 1 << 30, fcgat_b, s_nd, t_nd,
        25600, 480, 768, 768, 768, 100, V, 512, 0);
    bbox_kernel<<<3200, 256, 0, stream>>>(pos, fcbbox_w, fcbbox_b, s_bb, t_bb, V);

    // 8 GCN blocks
    for (int i = 0; i < 8; i++) {
        const float* thw = gcn_theta_w + (size_t)i * Cc * Cc;
        const float* thb = gcn_theta_b + (size_t)i * Cc;
        const float* phw = gcn_phi_w + (size_t)i * Cc * Cc;
        const float* gw  = gcn_g_w + (size_t)i * Cc * Cc;
        const float* gb  = gcn_g_b + (size_t)i * Cc;
        const float* Ww  = gcn_W_w + (size_t)i * Cc * Cc;
        const float* Wb  = gcn_W_b + (size_t)i * Cc;

        // compose Mw[c,d] = sum_j theta[j,c]*phi[j,d]  (TA, NN)
        gemm128_kernel<0, false, true, false><<<dim3(4, 4, 1), blk, 0, stream>>>(
            thw, phw, nullptr, 1 << 30, nullptr, nullptr, nullptr,
            512, 512, 512, 512, 512, 0, Mw, 512, 0);
        // compose WGT[c,o] = sum_j g[j,c]*W[o,j]  (TA, TB)
        gemm128_kernel<0, false, true, true><<<dim3(4, 4, 1), blk, 0, stream>>>(
            gw, Ww, nullptr, 1 << 30, nullptr, nullptr, nullptr,
            512, 512, 512, 512, 512, 0, WGT, 512, 0);
        // bias helper vectors (all-zero biases in this model, kept for generality)
        q2_kernel<<<2, 256, 0, stream>>>(phw, thb, q2);
        cconst_kernel<<<512, 64, 0, stream>>>(Ww, gb, Wb, cc);
        colterm_kernel<<<6400, 256, 0, stream>>>(V, q2, ct);

        // fused T | Z = V @ [Mw | WGT]  -> TZ (25600 x 1024)
        gemm128_kernel<0, false, false, false><<<dim3(200, 8, 1), blk, 0, stream>>>(
            V, Mw, WGT, 4, nullptr, nullptr, nullptr,
            25600, 1024, 512, 512, 512, 0, TZ, 1024, 0);

        // R = batched T_b @ V_b^T + ct  (per-b: 100x512 @ 512x100)
        gemm_kernel<0, false, true, 1><<<dim3(2, 2, 256), blk, 0, stream>>>(
            TZ, V, nullptr, nullptr, nullptr, ct, 100, 100, 512, 1024, 512, 0,
            Abuf, 100, 0, (long)Nn * 1024, (long)Nn * Cc, (long)Nn * Nn);
        softmax_rows_kernel<<<25600, 64, 0, stream>>>(Abuf);
        // Wy = batched A_b @ Z_b + cconst -> TZ cols 0..511 (per-b: 100x100 @ 100x512)
        gemm_kernel<0, false, false, 0><<<dim3(2, 8, 256), blk, 0, stream>>>(
            Abuf, TZ + 512, cc, nullptr, nullptr, nullptr, 100, 512, 100, 100, 1024, 0,
            TZ, 1024, 0, (long)Nn * Nn, (long)Nn * 1024, (long)Nn * 1024);

        // channel BN stats of Wy (deterministic 2-stage), then V += bn(Wy)
        wy_partial_kernel<<<dim3(8, 32, 1), 256, 0, stream>>>(TZ, 1024, part);
        wy_finalize_kernel<<<2, 256, 0, stream>>>(part, gcn_bn_g + (size_t)i * Cc,
                                                  gcn_bn_b + (size_t)i * Cc, s_g, t_g);
        residual_kernel<<<2048, 256, 0, stream>>>(V, TZ, 1024, s_g, t_g);
    }

    // l2norm over node dim + mean
    l2norm_mean_kernel<<<256, 512, 0, stream>>>(V, ALL);
    // final BN + tiny FC
    colstats_kernel<<<1536, 256, 0, stream>>>(ALL, 256, 1536, ffbn_g, ffbn_b, s_ff, t_ff);
    final_kernel<<<256, 256, 0, stream>>>(ALL, s_ff, t_ff, ff_w, ff_b, (float*)d_out);
}

// Round 3
// 6226.866 us; speedup vs baseline: 2.2309x; 1.2144x over previous
//
#include <hip/hip_runtime.h>
#include <cstddef>

#define EPS 1e-5f

constexpr int Bsz = 256;
constexpr int Nn  = 100;
constexpr int Cc  = 512;
constexpr int BN_ROWS = Bsz * Nn; // 25600

__device__ __forceinline__ void gload_lds16(const void* g, void* l) {
    __builtin_amdgcn_global_load_lds(
        (const __attribute__((address_space(1))) void*)g,
        (__attribute__((address_space(3))) void*)l, 16, 0, 0);
}

// ---------------- per-column stats over M rows (M <= 256), grid = Ccols ----------------
__global__ void colstats_kernel(const float* __restrict__ x, int M, int Ccols,
                                const float* __restrict__ g, const float* __restrict__ bb,
                                float* __restrict__ s, float* __restrict__ t) {
    int c = blockIdx.x;
    int r = threadIdx.x;
    float v = (r < M) ? x[(size_t)r * Ccols + c] : 0.f;
    __shared__ float ssum[256], ssq[256];
    ssum[r] = v; ssq[r] = v * v;
    __syncthreads();
    for (int off = 128; off > 0; off >>= 1) {
        if (r < off) { ssum[r] += ssum[r + off]; ssq[r] += ssq[r + off]; }
        __syncthreads();
    }
    if (r == 0) {
        float m   = ssum[0] / M;
        float var = ssq[0] / M - m * m;
        float sc  = g[c] * rsqrtf(var + EPS);
        s[c] = sc;
        t[c] = bb[c] - m * sc;
    }
}

// ---------------- small per-node-channel stats (pos: D=4), grid = Nn ----------------
__global__ void chstats_kernel(const float* __restrict__ x, int D,
                               const float* __restrict__ g, const float* __restrict__ bb,
                               float* __restrict__ s, float* __restrict__ t) {
    int n = blockIdx.x;
    int tid = threadIdx.x;
    int total = Bsz * D;
    float sum = 0.f, sq = 0.f;
    for (int idx = tid; idx < total; idx += blockDim.x) {
        int b = idx / D, d = idx - b * D;
        float v = x[((size_t)b * Nn + n) * D + d];
        sum += v; sq += v * v;
    }
    __shared__ float ssum[256], ssq[256];
    ssum[tid] = sum; ssq[tid] = sq;
    __syncthreads();
    for (int off = 128; off > 0; off >>= 1) {
        if (tid < off) { ssum[tid] += ssum[tid + off]; ssq[tid] += ssq[tid + off]; }
        __syncthreads();
    }
    if (tid == 0) {
        float m   = ssum[0] / total;
        float var = ssq[0] / total - m * m;
        float sc  = g[n] * rsqrtf(var + EPS);
        s[n] = sc;
        t[n] = bb[n] - m * sc;
    }
}

// ---------------- node-emb channel stats, two-stage: grid (100, 16) ----------------
__global__ void chstats_part_kernel(const float* __restrict__ x, float* __restrict__ npart) {
    int n = blockIdx.x, chunk = blockIdx.y;
    int tid = threadIdx.x;
    float sum = 0.f, sq = 0.f;
    // 16 rows (b) x 768 cols = 3072 float4
    for (int i = tid; i < 3072; i += 256) {
        int rrow = i / 192;
        int q = i - rrow * 192;
        float4 f = *(const float4*)(x + ((size_t)(chunk * 16 + rrow) * Nn + n) * 768 + q * 4);
        sum += f.x + f.y + f.z + f.w;
        sq  += f.x * f.x + f.y * f.y + f.z * f.z + f.w * f.w;
    }
    __shared__ float ss[256], s2[256];
    ss[tid] = sum; s2[tid] = sq;
    __syncthreads();
    for (int off = 128; off > 0; off >>= 1) {
        if (tid < off) { ss[tid] += ss[tid + off]; s2[tid] += s2[tid + off]; }
        __syncthreads();
    }
    if (tid == 0) {
        npart[chunk * 200 + n] = ss[0];
        npart[chunk * 200 + 100 + n] = s2[0];
    }
}

__global__ void chstats_fin_kernel(const float* __restrict__ npart,
                                   const float* __restrict__ g, const float* __restrict__ bb,
                                   float* __restrict__ s, float* __restrict__ t) {
    int n = threadIdx.x;
    if (n >= 100) return;
    float sum = 0.f, sq = 0.f;
    for (int c = 0; c < 16; c++) {
        sum += npart[c * 200 + n];
        sq  += npart[c * 200 + 100 + n];
    }
    const float total = 256.f * 768.f;
    float m   = sum / total;
    float var = sq / total - m * m;
    float sc  = g[n] * rsqrtf(var + EPS);
    s[n] = sc;
    t[n] = bb[n] - m * sc;
}

// ================= fast 128x128 tiled fp32 GEMM, 8x8 micro-tile =================
template <int NORM, bool ELU, bool TA, bool TB>
__global__ __launch_bounds__(256) void gemm128_kernel(
    const float* __restrict__ A, const float* __restrict__ B0,
    const float* __restrict__ B1, int nsplit,
    const float* __restrict__ bias,
    const float* __restrict__ s, const float* __restrict__ t,
    int M, int N, int K, int lda, int ldb, int mod,
    float* __restrict__ C, int ldc, int c_off) {
    __shared__ float As[16 * 132];
    __shared__ float Bs[16 * 132];
    constexpr int AS = TA ? 128 : 132;
    constexpr int BS = TB ? 132 : 128;

    int by = blockIdx.y;
    const float* B = (by < nsplit) ? B0 : B1;
    int bn = (by < nsplit ? by : by - nsplit) * 128;
    int bm = blockIdx.x * 128;
    int outcol0 = c_off + by * 128;

    int tid = threadIdx.x;
    int lane = tid & 63, wave = tid >> 6;
    int tx = tid & 15, ty = tid >> 4;

    float acc[8][8] = {};

    for (int k0 = 0; k0 < K; k0 += 16) {
        if constexpr (TA) {
#pragma unroll
            for (int i = 0; i < 2; i++) {
                int row = k0 + i * 8 + wave * 2 + (lane >> 5);
                const float* gp = A + (size_t)row * lda + bm + (lane & 31) * 4;
                gload_lds16(gp, (char*)As + ((i * 8 + wave * 2) * 128) * 4);
            }
        } else {
#pragma unroll
            for (int i = 0; i < 2; i++) {
                int id = tid + i * 256;
                int row = id >> 2, q = id & 3;
                int gr = bm + row;
                float4 f = *(const float4*)(A + (size_t)gr * lda + k0 + q * 4);
                if constexpr (NORM == 1) {
                    int kb = k0 + q * 4;
                    f.x = f.x * s[kb] + t[kb];     f.y = f.y * s[kb + 1] + t[kb + 1];
                    f.z = f.z * s[kb + 2] + t[kb + 2]; f.w = f.w * s[kb + 3] + t[kb + 3];
                } else if constexpr (NORM == 2) {
                    int n_ = gr % mod; float sc = s[n_], sh = t[n_];
                    f.x = f.x * sc + sh; f.y = f.y * sc + sh;
                    f.z = f.z * sc + sh; f.w = f.w * sc + sh;
                }
                As[(q * 4 + 0) * AS + row] = f.x;
                As[(q * 4 + 1) * AS + row] = f.y;
                As[(q * 4 + 2) * AS + row] = f.z;
                As[(q * 4 + 3) * AS + row] = f.w;
            }
        }
        if constexpr (!TB) {
#pragma unroll
            for (int i = 0; i < 2; i++) {
                int row = k0 + i * 8 + wave * 2 + (lane >> 5);
                const float* gp = B + (size_t)row * ldb + bn + (lane & 31) * 4;
                gload_lds16(gp, (char*)Bs + ((i * 8 + wave * 2) * 128) * 4);
            }
        } else {
#pragma unroll
            for (int i = 0; i < 2; i++) {
                int id = tid + i * 256;
                int row = id >> 2, q = id & 3;
                int gn = bn + row;
                float4 f = make_float4(0.f, 0.f, 0.f, 0.f);
                if (gn < N) f = *(const float4*)(B + (size_t)gn * ldb + k0 + q * 4);
                Bs[(q * 4 + 0) * BS + row] = f.x;
                Bs[(q * 4 + 1) * BS + row] = f.y;
                Bs[(q * 4 + 2) * BS + row] = f.z;
                Bs[(q * 4 + 3) * BS + row] = f.w;
            }
        }
        __syncthreads();
#pragma unroll
        for (int kk = 0; kk < 16; kk++) {
            float4 a0 = *(const float4*)&As[kk * AS + ty * 4];
            float4 a1 = *(const float4*)&As[kk * AS + ty * 4 + 64];
            float4 b0 = *(const float4*)&Bs[kk * BS + tx * 4];
            float4 b1 = *(const float4*)&Bs[kk * BS + tx * 4 + 64];
            float av[8] = {a0.x, a0.y, a0.z, a0.w, a1.x, a1.y, a1.z, a1.w};
            float bv[8] = {b0.x, b0.y, b0.z, b0.w, b1.x, b1.y, b1.z, b1.w};
#pragma unroll
            for (int i = 0; i < 8; i++)
#pragma unroll
                for (int j = 0; j < 8; j++)
                    acc[i][j] = fmaf(av[i], bv[j], acc[i][j]);
        }
        __syncthreads();
    }

#pragma unroll
    for (int i = 0; i < 8; i++) {
        int r = ty * 4 + (i & 3) + ((i & 4) ? 64 : 0);
        int gr = bm + r;
        float* crow = C + (size_t)gr * ldc + outcol0;
#pragma unroll
        for (int h = 0; h < 2; h++) {
            int cl = tx * 4 + h * 64;
            int gcol = bn + cl;
            if constexpr (TB) { if (gcol >= N) continue; }
            float4 o;
            o.x = acc[i][h * 4 + 0]; o.y = acc[i][h * 4 + 1];
            o.z = acc[i][h * 4 + 2]; o.w = acc[i][h * 4 + 3];
            if (bias) {
                o.x += bias[gcol]; o.y += bias[gcol + 1];
                o.z += bias[gcol + 2]; o.w += bias[gcol + 3];
            }
            if constexpr (ELU) {
                o.x = o.x > 0.f ? o.x : expm1f(o.x);
                o.y = o.y > 0.f ? o.y : expm1f(o.y);
                o.z = o.z > 0.f ? o.z : expm1f(o.z);
                o.w = o.w > 0.f ? o.w : expm1f(o.w);
            }
            *(float4*)(crow + cl) = o;
        }
    }
}

// ---------------- generic 64x64 tiled GEMM (small heads) ----------------
template <int NORM, bool ELU, bool TB>
__global__ void gemm_kernel(const float* __restrict__ A, const float* __restrict__ B,
                            const float* __restrict__ bias,
                            const float* __restrict__ s, const float* __restrict__ t,
                            int M, int N, int K, int lda, int ldb, int mod,
                            float* __restrict__ Cout, int ldc, int c_off) {
    __shared__ float As[16][65];
    __shared__ float Bs[16][65];

    int bm = blockIdx.x * 64, bn = blockIdx.y * 64;
    int tid = threadIdx.x;
    int tm = (tid >> 4) << 2;
    int tn = (tid & 15) << 2;
    float acc[4][4] = {};

    for (int k0 = 0; k0 < K; k0 += 16) {
#pragma unroll
        for (int i = 0; i < 4; i++) {
            int idx = tid + i * 256;
            {
                int rr = idx >> 4, kk = idx & 15;
                int gr = bm + rr, gk = k0 + kk;
                float av = 0.f;
                if (gr < M && gk < K) {
                    av = A[(size_t)gr * lda + gk];
                    if constexpr (NORM == 1) av = av * s[gk] + t[gk];
                    else if constexpr (NORM == 2) { int n_ = gr % mod; av = av * s[n_] + t[n_]; }
                }
                As[kk][rr] = av;
            }
            if constexpr (TB) {
                int nn = idx >> 4, kk = idx & 15;
                int gn = bn + nn, gk = k0 + kk;
                Bs[kk][nn] = (gn < N && gk < K) ? B[(size_t)gn * ldb + gk] : 0.f;
            } else {
                int kk = idx >> 6, nn = idx & 63;
                int gn = bn + nn, gk = k0 + kk;
                Bs[kk][nn] = (gn < N && gk < K) ? B[(size_t)gk * ldb + gn] : 0.f;
            }
        }
        __syncthreads();
#pragma unroll
        for (int kk = 0; kk < 16; kk++) {
            float a0[4], b0[4];
#pragma unroll
            for (int i = 0; i < 4; i++) a0[i] = As[kk][tm + i];
#pragma unroll
            for (int j = 0; j < 4; j++) b0[j] = Bs[kk][tn + j];
#pragma unroll
            for (int i = 0; i < 4; i++)
#pragma unroll
                for (int j = 0; j < 4; j++)
                    acc[i][j] = fmaf(a0[i], b0[j], acc[i][j]);
        }
        __syncthreads();
    }

#pragma unroll
    for (int i = 0; i < 4; i++) {
        int gr = bm + tm + i;
        if (gr >= M) continue;
#pragma unroll
        for (int j = 0; j < 4; j++) {
            int gn = bn + tn + j;
            if (gn >= N) continue;
            float v = acc[i][j] + (bias ? bias[gn] : 0.f);
            if constexpr (ELU) v = v > 0.f ? v : expm1f(v);
            Cout[(size_t)gr * ldc + c_off + gn] = v;
        }
    }
}

// ---------------- fused compose: z=0 Mw = th^T ph ; z=1 WGT = g^T W^T ----------------
__global__ __launch_bounds__(256) void compose_kernel(
    const float* __restrict__ th, const float* __restrict__ ph,
    const float* __restrict__ g, const float* __restrict__ W,
    float* __restrict__ Mw, float* __restrict__ WGT) {
    __shared__ float As[16][65];
    __shared__ float Bs[16][65];
    int z = blockIdx.z;
    const float* A = z ? g : th;
    int bm = blockIdx.x * 64, bn = blockIdx.y * 64;
    int tid = threadIdx.x;
    int tm = (tid >> 4) << 2;
    int tn = (tid & 15) << 2;
    float acc[4][4] = {};

    for (int k0 = 0; k0 < Cc; k0 += 16) {
#pragma unroll
        for (int i = 0; i < 4; i++) {
            int idx = tid + i * 256;
            { int kk = idx >> 6, m = idx & 63;
              As[kk][m] = A[(size_t)(k0 + kk) * Cc + bm + m]; }
            if (z == 0) {
                int kk = idx >> 6, n = idx & 63;
                Bs[kk][n] = ph[(size_t)(k0 + kk) * Cc + bn + n];
            } else {
                int n = idx >> 4, kk = idx & 15;
                Bs[kk][n] = W[(size_t)(bn + n) * Cc + k0 + kk];
            }
        }
        __syncthreads();
#pragma unroll
        for (int kk = 0; kk < 16; kk++) {
            float a0[4], b0[4];
#pragma unroll
            for (int i = 0; i < 4; i++) a0[i] = As[kk][tm + i];
#pragma unroll
            for (int j = 0; j < 4; j++) b0[j] = Bs[kk][tn + j];
#pragma unroll
            for (int i = 0; i < 4; i++)
#pragma unroll
                for (int j = 0; j < 4; j++)
                    acc[i][j] = fmaf(a0[i], b0[j], acc[i][j]);
        }
        __syncthreads();
    }
    float* out = z ? WGT : Mw;
#pragma unroll
    for (int i = 0; i < 4; i++)
#pragma unroll
        for (int j = 0; j < 4; j++)
            out[(size_t)(bm + tm + i) * Cc + bn + tn + j] = acc[i][j];
}

// ---------------- bbox head ----------------
__global__ void bbox_kernel(const float* __restrict__ pos, const float* __restrict__ w,
                            const float* __restrict__ bias, const float* __restrict__ s,
                            const float* __restrict__ t, float* __restrict__ V) {
    __shared__ float ws[32][4];
    int tid = threadIdx.x;
    if (tid < 128) ws[tid >> 2][tid & 3] = w[tid];
    __syncthreads();
    int r = blockIdx.x * 8 + (tid >> 5);
    int o = tid & 31;
    int n = r % Nn;
    float sc = s[n], sh = t[n];
    float p0 = pos[(size_t)r * 4 + 0] * sc + sh;
    float p1 = pos[(size_t)r * 4 + 1] * sc + sh;
    float p2 = pos[(size_t)r * 4 + 2] * sc + sh;
    float p3 = pos[(size_t)r * 4 + 3] * sc + sh;
    float acc = bias[o] + p0 * ws[o][0] + p1 * ws[o][1] + p2 * ws[o][2] + p3 * ws[o][3];
    acc = acc > 0.f ? acc : expm1f(acc);
    V[(size_t)r * Cc + 480 + o] = acc;
}

// ---------------- small compose helpers ----------------
__global__ void q2_kernel(const float* __restrict__ phi, const float* __restrict__ thb,
                          float* __restrict__ q2) {
    int c = blockIdx.x * 256 + threadIdx.x;
    float acc = 0.f;
    for (int j = 0; j < Cc; j++) acc += phi[(size_t)j * Cc + c] * thb[j];
    q2[c] = acc;
}
__global__ void cconst_kernel(const float* __restrict__ W, const float* __restrict__ gb,
                              const float* __restrict__ Wb, float* __restrict__ cc) {
    int o = blockIdx.x;
    int l = threadIdx.x; // 64
    float acc = 0.f;
    for (int j = l; j < Cc; j += 64) acc += W[(size_t)o * Cc + j] * gb[j];
    for (int off = 32; off > 0; off >>= 1) acc += __shfl_xor(acc, off, 64);
    if (l == 0) cc[o] = acc + Wb[o];
}
__global__ void colterm_kernel(const float* __restrict__ V, const float* __restrict__ q2,
                               float* __restrict__ ct) {
    int r = blockIdx.x * 4 + (threadIdx.x >> 6);
    int l = threadIdx.x & 63;
    const float* p = V + (size_t)r * Cc;
    float acc = 0.f;
    for (int c = l; c < Cc; c += 64) acc += p[c] * q2[c];
    for (int off = 32; off > 0; off >>= 1) acc += __shfl_xor(acc, off, 64);
    if (l == 0) ct[r] = acc;
}

// ================ fused per-batch attention: R -> softmax -> PV ================
// One block per batch b. TZ rows b*100..+99: cols 0..511 = T (read, then overwritten
// by Wy), cols 512..1023 = Z. V is (25600 x 512). ct per-row col-term, cc per-col bias.
__global__ __launch_bounds__(256) void attn_kernel(
    float* __restrict__ TZ, const float* __restrict__ V,
    const float* __restrict__ ct, const float* __restrict__ cc) {
    __shared__ float smem[23700];
    float* A_lds = smem;          // [100][105]
    float* Zs    = smem + 10500;  // [100][132]
    float* Ts    = smem + 10500;  // [32][105] (alias, phase 1)
    float* Vs    = smem + 13860;  // [32][105] (alias, phase 1)

    int b = blockIdx.x;
    size_t rowbase = (size_t)b * Nn;
    int tid = threadIdx.x;
    int tx = tid & 15, ty = tid >> 4;

    float acc[7][7];
#pragma unroll
    for (int i = 0; i < 7; i++)
#pragma unroll
        for (int j = 0; j < 7; j++) acc[i][j] = 0.f;

    // ---- phase 1: R = T_b @ V_b^T ----
    for (int k0 = 0; k0 < 512; k0 += 32) {
        __syncthreads();
        for (int i = tid; i < 1600; i += 256) {
            int isV = (i >= 800);
            int ii = isV ? i - 800 : i;
            int r = ii >> 3, q = ii & 7;
            const float* src = isV ? (V + (rowbase + r) * 512 + k0 + q * 4)
                                   : (TZ + (rowbase + r) * 1024 + k0 + q * 4);
            float4 f = *(const float4*)src;
            float* dst = (isV ? Vs : Ts) + r;
            dst[(q * 4 + 0) * 105] = f.x;
            dst[(q * 4 + 1) * 105] = f.y;
            dst[(q * 4 + 2) * 105] = f.z;
            dst[(q * 4 + 3) * 105] = f.w;
        }
        __syncthreads();
#pragma unroll 4
        for (int kk = 0; kk < 32; kk++) {
            float a[7], bb[7];
#pragma unroll
            for (int i = 0; i < 7; i++) a[i] = Ts[kk * 105 + ty * 7 + i];
#pragma unroll
            for (int j = 0; j < 7; j++) bb[j] = Vs[kk * 105 + tx * 7 + j];
#pragma unroll
            for (int i = 0; i < 7; i++)
#pragma unroll
                for (int j = 0; j < 7; j++)
                    acc[i][j] = fmaf(a[i], bb[j], acc[i][j]);
        }
    }
    __syncthreads();

    // ---- phase 2: write R + ct to LDS, softmax rows ----
    float ctv[7];
#pragma unroll
    for (int j = 0; j < 7; j++) {
        int c = tx * 7 + j;
        ctv[j] = (c < Nn) ? ct[rowbase + c] : 0.f;
    }
#pragma unroll
    for (int i = 0; i < 7; i++) {
        int r = ty * 7 + i;
        if (r >= Nn) continue;
#pragma unroll
        for (int j = 0; j < 7; j++) {
            int c = tx * 7 + j;
            if (c < Nn) A_lds[r * 105 + c] = acc[i][j] + ctv[j];
        }
    }
    __syncthreads();
    if (tid < Nn) {
        float* row = A_lds + tid * 105;
        float mx = -1e30f;
        for (int m = 0; m < Nn; m++) mx = fmaxf(mx, row[m]);
        float sm = 0.f;
        for (int m = 0; m < Nn; m++) { float e = expf(row[m] - mx); row[m] = e; sm += e; }
        float inv = 1.f / sm;
        for (int m = 0; m < Nn; m++) row[m] *= inv;
    }

    // ---- phase 3: Wy = A @ Z_b + cc, written over T cols ----
    for (int c0 = 0; c0 < 512; c0 += 128) {
        __syncthreads();
        for (int i = tid; i < 3200; i += 256) {
            int r = i >> 5, q = i & 31;
            float4 f = *(const float4*)(TZ + (rowbase + r) * 1024 + 512 + c0 + q * 4);
            *(float4*)&Zs[r * 132 + q * 4] = f;
        }
        __syncthreads();
        float acc2[7][8];
#pragma unroll
        for (int i = 0; i < 7; i++)
#pragma unroll
            for (int j = 0; j < 8; j++) acc2[i][j] = 0.f;
#pragma unroll 4
        for (int k = 0; k < Nn; k++) {
            float a[7];
#pragma unroll
            for (int i = 0; i < 7; i++) a[i] = A_lds[(ty * 7 + i) * 105 + k];
            float4 z0 = *(const float4*)&Zs[k * 132 + tx * 8];
            float4 z1 = *(const float4*)&Zs[k * 132 + tx * 8 + 4];
            float zv[8] = {z0.x, z0.y, z0.z, z0.w, z1.x, z1.y, z1.z, z1.w};
#pragma unroll
            for (int i = 0; i < 7; i++)
#pragma unroll
                for (int j = 0; j < 8; j++)
                    acc2[i][j] = fmaf(a[i], zv[j], acc2[i][j]);
        }
#pragma unroll
        for (int i = 0; i < 7; i++) {
            int r = ty * 7 + i;
            if (r >= Nn) continue;
            float* orow = TZ + (rowbase + r) * 1024 + c0 + tx * 8;
            int cg = c0 + tx * 8;
            float4 o0, o1;
            o0.x = acc2[i][0] + cc[cg + 0]; o0.y = acc2[i][1] + cc[cg + 1];
            o0.z = acc2[i][2] + cc[cg + 2]; o0.w = acc2[i][3] + cc[cg + 3];
            o1.x = acc2[i][4] + cc[cg + 4]; o1.y = acc2[i][5] + cc[cg + 5];
            o1.z = acc2[i][6] + cc[cg + 6]; o1.w = acc2[i][7] + cc[cg + 7];
            *(float4*)orow = o0;
            *(float4*)(orow + 4) = o1;
        }
    }
}

// ---------------- deterministic channel-BN stats for Wy ----------------
__global__ void wy_partial_kernel(const float* __restrict__ Wy, int ldw, float* __restrict__ part) {
    int tx = threadIdx.x & 63;
    int ty = threadIdx.x >> 6;
    int c  = blockIdx.x * 64 + tx;
    int r0 = blockIdx.y * 800;
    float sum = 0.f, sq = 0.f;
    for (int r = r0 + ty; r < r0 + 800; r += 4) {
        float v = Wy[(size_t)r * ldw + c];
        sum += v; sq += v * v;
    }
    __shared__ float ss[256], s2[256];
    ss[threadIdx.x] = sum; s2[threadIdx.x] = sq;
    __syncthreads();
    if (ty == 0) {
        sum = ss[tx] + ss[tx + 64] + ss[tx + 128] + ss[tx + 192];
        sq  = s2[tx] + s2[tx + 64] + s2[tx + 128] + s2[tx + 192];
        part[((size_t)blockIdx.y * 2 + 0) * Cc + c] = sum;
        part[((size_t)blockIdx.y * 2 + 1) * Cc + c] = sq;
    }
}

__global__ void wy_finalize_kernel(const float* __restrict__ part,
                                   const float* __restrict__ g, const float* __restrict__ bb,
                                   float* __restrict__ s, float* __restrict__ t) {
    int c = blockIdx.x * 256 + threadIdx.x;
    if (c >= Cc) return;
    float sum = 0.f, sq = 0.f;
    for (int y = 0; y < 32; y++) {
        sum += part[((size_t)y * 2 + 0) * Cc + c];
        sq  += part[((size_t)y * 2 + 1) * Cc + c];
    }
    float m   = sum / BN_ROWS;
    float var = sq / BN_ROWS - m * m;
    float sc  = g[c] * rsqrtf(var + EPS);
    s[c] = sc;
    t[c] = bb[c] - m * sc;
}

// ---------------- residual: V += Wy*s[c] + t[c] ----------------
__global__ void residual_kernel(float* __restrict__ V, const float* __restrict__ Wy, int ldw,
                                const float* __restrict__ s, const float* __restrict__ t) {
    size_t total4 = (size_t)BN_ROWS * Cc / 4;
    for (size_t i4 = (size_t)blockIdx.x * blockDim.x + threadIdx.x; i4 < total4;
         i4 += (size_t)gridDim.x * blockDim.x) {
        int row = (int)(i4 >> 7);
        int c = (int)(i4 & 127) * 4;
        float4 w = *(const float4*)(Wy + (size_t)row * ldw + c);
        float4 sv = *(const float4*)(s + c);
        float4 tv = *(const float4*)(t + c);
        float4 v = *(float4*)(V + (size_t)row * Cc + c);
        v.x += w.x * sv.x + tv.x; v.y += w.y * sv.y + tv.y;
        v.z += w.z * sv.z + tv.z; v.w += w.w * sv.w + tv.w;
        *(float4*)(V + (size_t)row * Cc + c) = v;
    }
}

// ---------------- l2norm over node dim + mean -> ALL[:, 512:1024] ----------------
__global__ void l2norm_mean_kernel(const float* __restrict__ V, float* __restrict__ ALL) {
    int b = blockIdx.x;
    int c = threadIdx.x; // 512
    float sum = 0.f, sq = 0.f;
    const float* p = V + (size_t)b * Nn * Cc + c;
    for (int n = 0; n < Nn; n++) {
        float v = p[(size_t)n * Cc];
        sum += v; sq += v * v;
    }
    ALL[(size_t)b * 1536 + 512 + c] = sum / (Nn * sqrtf(sq));
}

// ---------------- final: BN(all_feats) @ ff_w.T + ff_b -> (256,2) ----------------
__global__ void final_kernel(const float* __restrict__ ALL, const float* __restrict__ s,
                             const float* __restrict__ t, const float* __restrict__ w,
                             const float* __restrict__ bias, float* __restrict__ out) {
    int b = blockIdx.x;
    int tid = threadIdx.x; // 256
    float p0 = 0.f, p1 = 0.f;
    for (int k = tid; k < 1536; k += 256) {
        float af = ALL[(size_t)b * 1536 + k] * s[k] + t[k];
        p0 += af * w[k];
        p1 += af * w[1536 + k];
    }
    __shared__ float s0[256], s1[256];
    s0[tid] = p0; s1[tid] = p1;
    __syncthreads();
    for (int off = 128; off > 0; off >>= 1) {
        if (tid < off) { s0[tid] += s0[tid + off]; s1[tid] += s1[tid + off]; }
        __syncthreads();
    }
    if (tid == 0) {
        out[b * 2 + 0] = s0[0] + bias[0];
        out[b * 2 + 1] = s1[0] + bias[1];
    }
}

extern "C" void kernel_launch(void* const* d_in, const int* in_sizes, int n_in,
                              void* d_out, int out_size, void* d_ws, size_t ws_size,
                              hipStream_t stream) {
    const float* img   = (const float*)d_in[0];
    const float* txt   = (const float*)d_in[1];
    const float* node  = (const float*)d_in[2];
    const float* pos   = (const float*)d_in[3];
    const float* swinbn_g = (const float*)d_in[4];
    const float* swinbn_b = (const float*)d_in[5];
    const float* swinfc_w = (const float*)d_in[6];
    const float* swinfc_b = (const float*)d_in[7];
    const float* bntext_g = (const float*)d_in[8];
    const float* bntext_b = (const float*)d_in[9];
    const float* fctext_w = (const float*)d_in[10];
    const float* fctext_b = (const float*)d_in[11];
    const float* bngat_g  = (const float*)d_in[12];
    const float* bngat_b  = (const float*)d_in[13];
    const float* fcgat_w  = (const float*)d_in[14];
    const float* fcgat_b  = (const float*)d_in[15];
    const float* bnbbox_g = (const float*)d_in[16];
    const float* bnbbox_b = (const float*)d_in[17];
    const float* fcbbox_w = (const float*)d_in[18];
    const float* fcbbox_b = (const float*)d_in[19];
    const float* gcn_theta_w = (const float*)d_in[20];
    const float* gcn_theta_b = (const float*)d_in[21];
    const float* gcn_phi_w   = (const float*)d_in[22];
    const float* gcn_phi_b   = (const float*)d_in[23];
    const float* gcn_g_w     = (const float*)d_in[24];
    const float* gcn_g_b     = (const float*)d_in[25];
    const float* gcn_W_w     = (const float*)d_in[26];
    const float* gcn_W_b     = (const float*)d_in[27];
    const float* gcn_bn_g    = (const float*)d_in[28];
    const float* gcn_bn_b    = (const float*)d_in[29];
    const float* ffbn_g = (const float*)d_in[30];
    const float* ffbn_b = (const float*)d_in[31];
    const float* ff_w   = (const float*)d_in[32];
    const float* ff_b   = (const float*)d_in[33];

    float* ws = (float*)d_ws;
    const size_t VN = (size_t)BN_ROWS * Cc;       // 13,107,200
    float* V    = ws;
    float* TZ   = V + VN;                         // 26,214,400 (25600 x 1024)
    float* Abuf = TZ + VN * 2;                    // compose scratch
    float* Mw   = Abuf;
    float* WGT  = Abuf + (size_t)Cc * Cc;
    float* ALL  = Abuf + (size_t)Bsz * Nn * Nn;   // 393,216
    float* ct   = ALL + (size_t)Bsz * 1536;       // 25,600
    float* part = ct + BN_ROWS;                   // 32,768 (also npart scratch)
    float* st   = part + 64 * Cc;
    float* s_img = st;            float* t_img = s_img + 1024;
    float* s_txt = t_img + 1024;  float* t_txt = s_txt + 768;
    float* s_nd  = t_txt + 768;   float* t_nd  = s_nd + 128;
    float* s_bb  = t_nd + 128;    float* t_bb  = s_bb + 128;
    float* s_g   = t_bb + 128;    float* t_g   = s_g + 512;
    float* s_ff  = t_g + 512;     float* t_ff  = s_ff + 1536;
    float* q2    = t_ff + 1536;   float* cc    = q2 + 512;

    dim3 blk(256);

    // input BN stats
    colstats_kernel<<<1024, 256, 0, stream>>>(img, 256, 1024, swinbn_g, swinbn_b, s_img, t_img);
    colstats_kernel<<<768, 256, 0, stream>>>(txt, 256, 768, bntext_g, bntext_b, s_txt, t_txt);
    chstats_part_kernel<<<dim3(100, 16, 1), 256, 0, stream>>>(node, part);
    chstats_fin_kernel<<<1, 128, 0, stream>>>(part, bngat_g, bngat_b, s_nd, t_nd);
    chstats_kernel<<<100, 256, 0, stream>>>(pos, 4, bnbbox_g, bnbbox_b, s_bb, t_bb);

    // heads
    gemm_kernel<1, true, true><<<dim3(4, 8, 1), blk, 0, stream>>>(
        img, swinfc_w, swinfc_b, s_img, t_img, 256, 512, 1024, 1024, 1024, 0,
        ALL, 1536, 0);
    gemm_kernel<1, true, true><<<dim3(4, 8, 1), blk, 0, stream>>>(
        txt, fctext_w, fctext_b, s_txt, t_txt, 256, 512, 768, 768, 768, 0,
        ALL, 1536, 1024);
    gemm128_kernel<2, true, false, true><<<dim3(200, 4, 1), blk, 0, stream>>>(
        node, fcgat_w, nullptr, 1 << 30, fcgat_b, s_nd, t_nd,
        25600, 480, 768, 768, 768, 100, V, 512, 0);
    bbox_kernel<<<3200, 256, 0, stream>>>(pos, fcbbox_w, fcbbox_b, s_bb, t_bb, V);

    // 8 GCN blocks
    for (int i = 0; i < 8; i++) {
        const float* thw = gcn_theta_w + (size_t)i * Cc * Cc;
        const float* thb = gcn_theta_b + (size_t)i * Cc;
        const float* phw = gcn_phi_w + (size_t)i * Cc * Cc;
        const float* gw  = gcn_g_w + (size_t)i * Cc * Cc;
        const float* gb  = gcn_g_b + (size_t)i * Cc;
        const float* Ww  = gcn_W_w + (size_t)i * Cc * Cc;
        const float* Wb  = gcn_W_b + (size_t)i * Cc;

        // fused compose: Mw = th^T ph, WGT = g^T W^T
        compose_kernel<<<dim3(8, 8, 2), blk, 0, stream>>>(thw, phw, gw, Ww, Mw, WGT);
        // bias helper vectors
        q2_kernel<<<2, 256, 0, stream>>>(phw, thb, q2);
        cconst_kernel<<<512, 64, 0, stream>>>(Ww, gb, Wb, cc);
        colterm_kernel<<<6400, 256, 0, stream>>>(V, q2, ct);

        // fused T | Z = V @ [Mw | WGT]  -> TZ (25600 x 1024)
        gemm128_kernel<0, false, false, false><<<dim3(200, 8, 1), blk, 0, stream>>>(
            V, Mw, WGT, 4, nullptr, nullptr, nullptr,
            25600, 1024, 512, 512, 512, 0, TZ, 1024, 0);

        // fused attention: R = T V^T + ct -> softmax -> Wy = A Z + cc (into TZ[:,0:512])
        attn_kernel<<<256, 256, 0, stream>>>(TZ, V, ct, cc);

        // channel BN stats of Wy, then V += bn(Wy)
        wy_partial_kernel<<<dim3(8, 32, 1), 256, 0, stream>>>(TZ, 1024, part);
        wy_finalize_kernel<<<2, 256, 0, stream>>>(part, gcn_bn_g + (size_t)i * Cc,
                                                  gcn_bn_b + (size_t)i * Cc, s_g, t_g);
        residual_kernel<<<2048, 256, 0, stream>>>(V, TZ, 1024, s_g, t_g);
    }

    // l2norm over node dim + mean
    l2norm_mean_kernel<<<256, 512, 0, stream>>>(V, ALL);
    // final BN + tiny FC
    colstats_kernel<<<1536, 256, 0, stream>>>(ALL, 256, 1536, ffbn_g, ffbn_b, s_ff, t_ff);
    final_kernel<<<256, 256, 0, stream>>>(ALL, s_ff, t_ff, ff_w, ff_b, (float*)d_out);
}